// Round 1
// baseline (2042.141 us; speedup 1.0000x reference)
//
#include <hip/hip_runtime.h>
#include <hip/hip_bf16.h>
#include <math.h>

#define BBATCH 4
#define NHEAD  8
#define TSEQ   2048
#define NDIM   256
#define DDIM   512

typedef float f32x4 __attribute__((ext_vector_type(4)));
typedef short bf16x8 __attribute__((ext_vector_type(8)));

__device__ __forceinline__ unsigned short f2bf(float f) {
  __hip_bfloat16 h = __float2bfloat16(f);
  return *reinterpret_cast<unsigned short*>(&h);
}
__device__ __forceinline__ float bf2f(unsigned short u) {
  __hip_bfloat16 h;
  *reinterpret_cast<unsigned short*>(&h) = u;
  return __bfloat162float(h);
}
__device__ __forceinline__ f32x4 mfma16(bf16x8 a, bf16x8 b, f32x4 c) {
  return __builtin_amdgcn_mfma_f32_16x16x32_bf16(a, b, c, 0, 0, 0);
}

// ---------------- Kernel 1: RoPE(Q) -> QR bf16 --------------------------
__global__ __launch_bounds__(256) void rope_kernel(const float* __restrict__ Q,
                                                   unsigned short* __restrict__ QR) {
  long idx = (long)blockIdx.x * 256 + threadIdx.x;     // pair index
  int pair = (int)(idx & 127);                         // N/2 = 128
  long row = idx >> 7;                                 // b*NH*T row
  int t = (int)(row & (TSEQ - 1));
  float2 q = reinterpret_cast<const float2*>(Q)[idx];
  float freq = exp2f(-(float)pair * 0.125f) * 0.15915494309189535f; // 2^(-p/8)/(2pi)
  float phase = (float)t * freq;
  float ph = (phase - floorf(phase)) * 6.283185307179586f;
  float s, c;
  sincosf(ph, &s, &c);
  float o0 = q.x * c - q.y * s;
  float o1 = q.y * c + q.x * s;
  unsigned int pk = (unsigned int)f2bf(o0) | ((unsigned int)f2bf(o1) << 16);
  reinterpret_cast<unsigned int*>(QR)[idx] = pk;
}

// ---------------- Kernel 2: transpose + cast f32[R][C] -> bf16[C][R] ----
__global__ __launch_bounds__(256) void transpose_cast_kernel(
    const float* __restrict__ in, unsigned short* __restrict__ out, int R, int C) {
  __shared__ float tile[64][65];
  long mat = blockIdx.z;
  const float* src = in + mat * (long)R * C;
  unsigned short* dst = out + mat * (long)R * C;
  int c0 = blockIdx.x * 64, r0 = blockIdx.y * 64;
  int tr = threadIdx.x >> 4;          // 0..15
  int tc = (threadIdx.x & 15) * 4;    // 0..60
#pragma unroll
  for (int p = 0; p < 4; ++p) {
    int r = tr + p * 16;
    float4 v = *reinterpret_cast<const float4*>(&src[(long)(r0 + r) * C + c0 + tc]);
    tile[r][tc + 0] = v.x; tile[r][tc + 1] = v.y;
    tile[r][tc + 2] = v.z; tile[r][tc + 3] = v.w;
  }
  __syncthreads();
#pragma unroll
  for (int p = 0; p < 4; ++p) {
    int c = tr + p * 16;
    ushort4 o;
    o.x = f2bf(tile[tc + 0][c]);
    o.y = f2bf(tile[tc + 1][c]);
    o.z = f2bf(tile[tc + 2][c]);
    o.w = f2bf(tile[tc + 3][c]);
    *reinterpret_cast<ushort4*>(&dst[(long)(c0 + c) * R + r0 + tc]) = o;
  }
}

// ---------------- Kernel 3: Qm/Km = l2norm(x @ W^T), bf16x3-split MFMA --
__global__ __launch_bounds__(512) void qkm_kernel(
    const float* __restrict__ x,    // [8192][512]
    const float* __restrict__ wq,   // [256][512]
    const float* __restrict__ wk,   // [256][512]
    unsigned short* __restrict__ Qm,  // [8192][256] bf16
    float* __restrict__ Km) {         // [8192][256] f32
  const bool isK = (blockIdx.y == 1);
  const float* w = isK ? wk : wq;
  int r0 = blockIdx.x * 64;
  int wave = threadIdx.x >> 6, lane = threadIdx.x & 63;
  int wm = wave >> 2, wn = wave & 3;
  int khi = lane >> 4, l16 = lane & 15;
  __shared__ unsigned short Ahi[64 * 32], Alo[64 * 32];
  __shared__ unsigned short Bhi[256 * 32], Blo[256 * 32];
  __shared__ float red[4][64];
  f32x4 acc[2][4] = {};
  for (int k0 = 0; k0 < 512; k0 += 32) {
    { // stage A (x rows): 64x32, one float4 per thread
      int row = threadIdx.x >> 3;
      int kc = (threadIdx.x & 7) * 4;
      float4 v = *reinterpret_cast<const float4*>(&x[(long)(r0 + row) * 512 + k0 + kc]);
      float vv[4] = {v.x, v.y, v.z, v.w};
      unsigned int hx[2], lx[2];
      unsigned short h0 = f2bf(vv[0]), h1 = f2bf(vv[1]), h2 = f2bf(vv[2]), h3 = f2bf(vv[3]);
      hx[0] = (unsigned)h0 | ((unsigned)h1 << 16);
      hx[1] = (unsigned)h2 | ((unsigned)h3 << 16);
      lx[0] = (unsigned)f2bf(vv[0] - bf2f(h0)) | ((unsigned)f2bf(vv[1] - bf2f(h1)) << 16);
      lx[1] = (unsigned)f2bf(vv[2] - bf2f(h2)) | ((unsigned)f2bf(vv[3] - bf2f(h3)) << 16);
      int byt = row * 64 + ((kc * 2) ^ ((row & 3) << 4));
      *reinterpret_cast<uint2*>((char*)Ahi + byt) = make_uint2(hx[0], hx[1]);
      *reinterpret_cast<uint2*>((char*)Alo + byt) = make_uint2(lx[0], lx[1]);
    }
#pragma unroll
    for (int p = 0; p < 4; ++p) { // stage B (w rows): 256x32
      int idx2 = threadIdx.x + p * 512;
      int row = idx2 >> 3;
      int kc = (idx2 & 7) * 4;
      float4 v = *reinterpret_cast<const float4*>(&w[(long)row * 512 + k0 + kc]);
      float vv[4] = {v.x, v.y, v.z, v.w};
      unsigned short h0 = f2bf(vv[0]), h1 = f2bf(vv[1]), h2 = f2bf(vv[2]), h3 = f2bf(vv[3]);
      unsigned int hx0 = (unsigned)h0 | ((unsigned)h1 << 16);
      unsigned int hx1 = (unsigned)h2 | ((unsigned)h3 << 16);
      unsigned int lx0 = (unsigned)f2bf(vv[0] - bf2f(h0)) | ((unsigned)f2bf(vv[1] - bf2f(h1)) << 16);
      unsigned int lx1 = (unsigned)f2bf(vv[2] - bf2f(h2)) | ((unsigned)f2bf(vv[3] - bf2f(h3)) << 16);
      int byt = row * 64 + ((kc * 2) ^ ((row & 3) << 4));
      *reinterpret_cast<uint2*>((char*)Bhi + byt) = make_uint2(hx0, hx1);
      *reinterpret_cast<uint2*>((char*)Blo + byt) = make_uint2(lx0, lx1);
    }
    __syncthreads();
    bf16x8 ah[2], al[2], bh[4], bl[4];
#pragma unroll
    for (int mi = 0; mi < 2; ++mi) {
      int row = wm * 32 + mi * 16 + l16;
      int byt = row * 64 + ((khi * 16) ^ ((row & 3) << 4));
      ah[mi] = *reinterpret_cast<const bf16x8*>((const char*)Ahi + byt);
      al[mi] = *reinterpret_cast<const bf16x8*>((const char*)Alo + byt);
    }
#pragma unroll
    for (int ni = 0; ni < 4; ++ni) {
      int row = wn * 64 + ni * 16 + l16;
      int byt = row * 64 + ((khi * 16) ^ ((row & 3) << 4));
      bh[ni] = *reinterpret_cast<const bf16x8*>((const char*)Bhi + byt);
      bl[ni] = *reinterpret_cast<const bf16x8*>((const char*)Blo + byt);
    }
#pragma unroll
    for (int mi = 0; mi < 2; ++mi)
#pragma unroll
      for (int ni = 0; ni < 4; ++ni) {
        acc[mi][ni] = mfma16(ah[mi], bh[ni], acc[mi][ni]);
        acc[mi][ni] = mfma16(ah[mi], bl[ni], acc[mi][ni]);
        acc[mi][ni] = mfma16(al[mi], bh[ni], acc[mi][ni]);
      }
    __syncthreads();
  }
  // l2norm over the 256 output cols
  float part[2][4];
#pragma unroll
  for (int mi = 0; mi < 2; ++mi)
#pragma unroll
    for (int r = 0; r < 4; ++r) {
      float s = 0.f;
#pragma unroll
      for (int ni = 0; ni < 4; ++ni) s += acc[mi][ni][r] * acc[mi][ni][r];
      part[mi][r] = s;
    }
#pragma unroll
  for (int off = 1; off < 16; off <<= 1)
#pragma unroll
    for (int mi = 0; mi < 2; ++mi)
#pragma unroll
      for (int r = 0; r < 4; ++r) part[mi][r] += __shfl_xor(part[mi][r], off);
  if (l16 == 0) {
#pragma unroll
    for (int mi = 0; mi < 2; ++mi)
#pragma unroll
      for (int r = 0; r < 4; ++r)
        red[wn][wm * 32 + mi * 16 + khi * 4 + r] = part[mi][r];
  }
  __syncthreads();
#pragma unroll
  for (int mi = 0; mi < 2; ++mi)
#pragma unroll
    for (int r = 0; r < 4; ++r) {
      int row = wm * 32 + mi * 16 + khi * 4 + r;
      float ss = red[0][row] + red[1][row] + red[2][row] + red[3][row];
      float scale = 1.f / fmaxf(sqrtf(ss), 1e-12f);
#pragma unroll
      for (int ni = 0; ni < 4; ++ni) {
        int col = wn * 64 + ni * 16 + l16;
        float val = acc[mi][ni][r] * scale;
        if (isK) Km[(long)(r0 + row) * 256 + col] = val;
        else     Qm[(long)(r0 + row) * 256 + col] = f2bf(val);
      }
    }
}

// ---------------- Kernel 4: beta = sigmoid(x @ beta_w^T) ----------------
__global__ __launch_bounds__(64) void beta_kernel(const float* __restrict__ x,
                                                  const float* __restrict__ bw,
                                                  float* __restrict__ beta) {
  long row = blockIdx.x;
  int lane = threadIdx.x;
  const float* xr = x + row * 512;
  float xv[8];
#pragma unroll
  for (int j = 0; j < 8; ++j) xv[j] = xr[lane + j * 64];
#pragma unroll
  for (int h = 0; h < 8; ++h) {
    const float* wr = bw + h * 512;
    float p = 0.f;
#pragma unroll
    for (int j = 0; j < 8; ++j) p += xv[j] * wr[lane + j * 64];
#pragma unroll
    for (int off = 32; off > 0; off >>= 1) p += __shfl_down(p, off);
    if (lane == 0) beta[row * 8 + h] = 1.f / (1.f + expf(-p));
  }
}

// ---------------- Kernel 5: delta-rule scan -> M_new (all f32) ----------
__global__ __launch_bounds__(64) void scan_kernel(
    const float* __restrict__ Km,   // [B*T][256]
    const float* __restrict__ xn,   // [B][T][512]
    const float* __restrict__ beta, // [B*T][8]
    const float* __restrict__ M0,   // [BH][256][512]
    float* __restrict__ Mout) {
  int blk = blockIdx.x;          // 2048 = 32 bh * 64 dchunks
  int dch = blk & 63, bh = blk >> 6;
  int b = bh >> 3, h = bh & 7;
  int d0 = dch * 8;
  int lane = threadIdx.x;
  int nq = lane >> 3;            // 0..7 -> 32 n-rows each
  int dc = lane & 7;
  int d = d0 + dc;
  int nbase = nq * 32;
  float m[32];
  const float* M0p = M0 + (long)bh * 256 * 512;
#pragma unroll
  for (int i = 0; i < 32; ++i) m[i] = M0p[(long)(nbase + i) * 512 + d];
  const float* kb = Km + (long)b * TSEQ * 256 + nbase;
  const float* vb = xn + (long)b * TSEQ * 512 + d;
  const float* bb = beta + (long)b * TSEQ * 8 + h;
  float4 kreg[8];
#pragma unroll
  for (int j = 0; j < 8; ++j) kreg[j] = *reinterpret_cast<const float4*>(kb + j * 4);
  for (int t = 0; t < TSEQ; ++t) {
    int tn = (t + 1 < TSEQ) ? (t + 1) : (TSEQ - 1);
    const float* knrow = kb + (long)tn * 256;
    float4 kn[8];
#pragma unroll
    for (int j = 0; j < 8; ++j) kn[j] = *reinterpret_cast<const float4*>(knrow + j * 4);
    float vv = vb[(long)t * 512];
    float btv = bb[(long)t * 8];
    float p0 = 0.f, p1 = 0.f, p2 = 0.f, p3 = 0.f;
#pragma unroll
    for (int j = 0; j < 8; ++j) {
      p0 = fmaf(kreg[j].x, m[j * 4 + 0], p0);
      p1 = fmaf(kreg[j].y, m[j * 4 + 1], p1);
      p2 = fmaf(kreg[j].z, m[j * 4 + 2], p2);
      p3 = fmaf(kreg[j].w, m[j * 4 + 3], p3);
    }
    float p = (p0 + p1) + (p2 + p3);
    p += __shfl_xor(p, 8);
    p += __shfl_xor(p, 16);
    p += __shfl_xor(p, 32);
    float delta = btv * (vv - p);
#pragma unroll
    for (int j = 0; j < 8; ++j) {
      m[j * 4 + 0] = fmaf(kreg[j].x, delta, m[j * 4 + 0]);
      m[j * 4 + 1] = fmaf(kreg[j].y, delta, m[j * 4 + 1]);
      m[j * 4 + 2] = fmaf(kreg[j].z, delta, m[j * 4 + 2]);
      m[j * 4 + 3] = fmaf(kreg[j].w, delta, m[j * 4 + 3]);
    }
#pragma unroll
    for (int j = 0; j < 8; ++j) kreg[j] = kn[j];
  }
  float* Mo = Mout + (long)bh * 256 * 512;
#pragma unroll
  for (int i = 0; i < 32; ++i) Mo[(long)(nbase + i) * 512 + d] = m[i];
}

// ---------------- Kernel 6: causal attention y_standard -----------------
// per block: (b,h), 128 t-rows, 256 d-cols; loop s-tiles of 64
__global__ __launch_bounds__(512) void attn_kernel(
    const unsigned short* __restrict__ QR,  // [BH][T][256] bf16
    const unsigned short* __restrict__ Vt,  // [BH][512][T] bf16
    float* __restrict__ Y) {                // [BH][T][512] f32
  int bt = blockIdx.x;
  int bh = blockIdx.y;
  int dch = blockIdx.z;
  int t0 = bt * 128, d0 = dch * 256;
  int wave = threadIdx.x >> 6, lane = threadIdx.x & 63;
  int wr = wave >> 2, wc = wave & 3;
  int khi = lane >> 4, l16 = lane & 15;
  __shared__ unsigned short K_lds[64 * 256];  // 32KB, swizzled
  __shared__ unsigned short S_lds[128 * 64];  // 16KB, swizzled
  const unsigned short* QRb = QR + (long)bh * TSEQ * 256;
  const unsigned short* Vtb = Vt + (long)bh * 512 * TSEQ;
  bf16x8 qa[8];
  {
    int trow = t0 + wave * 16 + l16;
    const unsigned short* qp = QRb + (long)trow * 256 + khi * 8;
#pragma unroll
    for (int ks = 0; ks < 8; ++ks) qa[ks] = *reinterpret_cast<const bf16x8*>(qp + ks * 32);
  }
  f32x4 acc[4][4] = {};
  int nst = bt * 2 + 2;
  for (int st = 0; st < nst; ++st) {
    int s0 = st * 64;
#pragma unroll
    for (int p = 0; p < 4; ++p) {   // stage K tile 64x256 bf16
      int row = (threadIdx.x >> 5) + p * 16;
      int nc = (threadIdx.x & 31) * 8;
      bf16x8 v = *reinterpret_cast<const bf16x8*>(QRb + (long)(s0 + row) * 256 + nc);
      *reinterpret_cast<bf16x8*>((char*)K_lds + row * 512 + ((nc * 2) ^ ((row & 7) << 4))) = v;
    }
    __syncthreads();
    // phase 1: S = Q K^T (wave -> 16 rows x 64 cols)
    f32x4 sacc[4] = {};
#pragma unroll
    for (int ks = 0; ks < 8; ++ks) {
#pragma unroll
      for (int fc = 0; fc < 4; ++fc) {
        int srow = fc * 16 + l16;
        bf16x8 kf = *reinterpret_cast<const bf16x8*>(
            (const char*)K_lds + srow * 512 + ((ks * 64 + khi * 16) ^ ((srow & 7) << 4)));
        sacc[fc] = mfma16(qa[ks], kf, sacc[fc]);
      }
    }
    // mask (strict lower) + cast + store to S_lds
#pragma unroll
    for (int fc = 0; fc < 4; ++fc)
#pragma unroll
      for (int r = 0; r < 4; ++r) {
        int srow = wave * 16 + khi * 4 + r;   // local t row
        int scol = fc * 16 + l16;             // local s col
        float v = ((s0 + scol) < (t0 + srow)) ? sacc[fc][r] : 0.f;
        *reinterpret_cast<unsigned short*>(
            (char*)S_lds + srow * 128 + ((scol * 2) ^ ((srow & 7) << 4))) = f2bf(v);
      }
    __syncthreads();
    // phase 2: O += S @ V  (wave tile 64x64)
#pragma unroll
    for (int k2 = 0; k2 < 2; ++k2) {
      bf16x8 af[4], bfv[4];
#pragma unroll
      for (int mi = 0; mi < 4; ++mi) {
        int row = wr * 64 + mi * 16 + l16;
        af[mi] = *reinterpret_cast<const bf16x8*>(
            (const char*)S_lds + row * 128 + ((k2 * 64 + khi * 16) ^ ((row & 7) << 4)));
      }
#pragma unroll
      for (int ni = 0; ni < 4; ++ni) {
        int d = d0 + wc * 64 + ni * 16 + l16;
        bfv[ni] = *reinterpret_cast<const bf16x8*>(Vtb + (long)d * TSEQ + s0 + k2 * 32 + khi * 8);
      }
#pragma unroll
      for (int mi = 0; mi < 4; ++mi)
#pragma unroll
        for (int ni = 0; ni < 4; ++ni)
          acc[mi][ni] = mfma16(af[mi], bfv[ni], acc[mi][ni]);
    }
    __syncthreads();
  }
  float* yb = Y + (long)bh * TSEQ * 512;
#pragma unroll
  for (int mi = 0; mi < 4; ++mi)
#pragma unroll
    for (int ni = 0; ni < 4; ++ni)
#pragma unroll
      for (int r = 0; r < 4; ++r) {
        int trow = t0 + wr * 64 + mi * 16 + khi * 4 + r;
        int d = d0 + wc * 64 + ni * 16 + l16;
        yb[(long)trow * 512 + d] = acc[mi][ni][r];
      }
}

// ---------------- Kernel 7: y_memory GEMM + LN + gated combine ----------
__global__ __launch_bounds__(512) void combine_kernel(
    const unsigned short* __restrict__ Qm,   // [B*T][256] bf16
    const unsigned short* __restrict__ M0t,  // [BH][512][256] bf16
    const float* __restrict__ mg,            // [NH]
    float* __restrict__ Y) {                 // [BH][T][512] in-place
  int t0 = blockIdx.x * 64;
  int bh = blockIdx.y;
  int b = bh >> 3, h = bh & 7;
  int wv = threadIdx.x >> 6, lane = threadIdx.x & 63;
  int khi = lane >> 4, l16 = lane & 15;
  __shared__ unsigned short A_lds[64 * 256];
  __shared__ float red_s[8][64], red_q[8][64];
  __shared__ float mu_s[64], inv_s[64];
  {
    const unsigned short* src = Qm + ((long)b * TSEQ + t0) * 256;
#pragma unroll
    for (int p = 0; p < 4; ++p) {
      int row = (threadIdx.x >> 5) + p * 16;
      int nc = (threadIdx.x & 31) * 8;
      bf16x8 v = *reinterpret_cast<const bf16x8*>(src + (long)row * 256 + nc);
      *reinterpret_cast<bf16x8*>((char*)A_lds + row * 512 + ((nc * 2) ^ ((row & 7) << 4))) = v;
    }
  }
  __syncthreads();
  f32x4 acc[4][4] = {};
  const unsigned short* Bp = M0t + (long)bh * 512 * 256;
#pragma unroll
  for (int ks = 0; ks < 8; ++ks) {
    bf16x8 a[4], bfr[4];
#pragma unroll
    for (int mi = 0; mi < 4; ++mi) {
      int row = mi * 16 + l16;
      a[mi] = *reinterpret_cast<const bf16x8*>(
          (const char*)A_lds + row * 512 + ((ks * 64 + khi * 16) ^ ((row & 7) << 4)));
    }
#pragma unroll
    for (int ni = 0; ni < 4; ++ni) {
      int d = wv * 64 + ni * 16 + l16;
      bfr[ni] = *reinterpret_cast<const bf16x8*>(Bp + (long)d * 256 + ks * 32 + khi * 8);
    }
#pragma unroll
    for (int mi = 0; mi < 4; ++mi)
#pragma unroll
      for (int ni = 0; ni < 4; ++ni)
        acc[mi][ni] = mfma16(a[mi], bfr[ni], acc[mi][ni]);
  }
  // LayerNorm stats over D=512 (8 waves x 64 cols)
  float ps[4][4], pq[4][4];
#pragma unroll
  for (int mi = 0; mi < 4; ++mi)
#pragma unroll
    for (int r = 0; r < 4; ++r) {
      float s = 0.f, q = 0.f;
#pragma unroll
      for (int ni = 0; ni < 4; ++ni) {
        float v = acc[mi][ni][r];
        s += v; q += v * v;
      }
      ps[mi][r] = s; pq[mi][r] = q;
    }
#pragma unroll
  for (int off = 1; off < 16; off <<= 1)
#pragma unroll
    for (int mi = 0; mi < 4; ++mi)
#pragma unroll
      for (int r = 0; r < 4; ++r) {
        ps[mi][r] += __shfl_xor(ps[mi][r], off);
        pq[mi][r] += __shfl_xor(pq[mi][r], off);
      }
  if (l16 == 0) {
#pragma unroll
    for (int mi = 0; mi < 4; ++mi)
#pragma unroll
      for (int r = 0; r < 4; ++r) {
        int row = mi * 16 + khi * 4 + r;
        red_s[wv][row] = ps[mi][r];
        red_q[wv][row] = pq[mi][r];
      }
  }
  __syncthreads();
  if (threadIdx.x < 64) {
    float s = 0.f, q = 0.f;
#pragma unroll
    for (int w2 = 0; w2 < 8; ++w2) { s += red_s[w2][threadIdx.x]; q += red_q[w2][threadIdx.x]; }
    float mu = s / 512.f;
    float var = q / 512.f - mu * mu;
    mu_s[threadIdx.x] = mu;
    inv_s[threadIdx.x] = rsqrtf(var + 1e-5f);
  }
  __syncthreads();
  float gate = 1.f / (1.f + expf(-mg[h]));
  float omg = 1.f - gate;
  float* yb = Y + ((long)bh * TSEQ + t0) * 512;
#pragma unroll
  for (int mi = 0; mi < 4; ++mi)
#pragma unroll
    for (int r = 0; r < 4; ++r) {
      int row = mi * 16 + khi * 4 + r;
      float mu = mu_s[row], inv = inv_s[row];
#pragma unroll
      for (int ni = 0; ni < 4; ++ni) {
        int d = wv * 64 + ni * 16 + l16;
        long off = (long)row * 512 + d;
        float ymv = (acc[mi][ni][r] - mu) * inv;
        yb[off] = omg * yb[off] + gate * ymv;
      }
    }
}

// ---------------- host launcher -----------------------------------------
extern "C" void kernel_launch(void* const* d_in, const int* in_sizes, int n_in,
                              void* d_out, int out_size, void* d_ws, size_t ws_size,
                              hipStream_t stream) {
  const float* Q      = (const float*)d_in[0];
  const float* V      = (const float*)d_in[1];
  const float* x_raw  = (const float*)d_in[2];
  const float* x_next = (const float*)d_in[3];
  const float* wq     = (const float*)d_in[4];
  const float* wk     = (const float*)d_in[5];
  const float* bw     = (const float*)d_in[6];
  const float* mg     = (const float*)d_in[7];
  const float* M0     = (const float*)d_in[8];
  float* y = (float*)d_out;
  float* Mout = y + (long)32 * 2048 * 512;   // y is B*NH*T*D = 33,554,432 floats

  char* ws = (char*)d_ws;
  unsigned short* QR  = (unsigned short*)(ws);                 // 33,554,432 B
  unsigned short* Vt  = (unsigned short*)(ws + 33554432);      // 67,108,864 B
  unsigned short* M0t = (unsigned short*)(ws + 100663296);     //  8,388,608 B
  unsigned short* Qm  = (unsigned short*)(ws + 109051904);     //  4,194,304 B
  float*  Km          = (float*)(ws + 113246208);              //  8,388,608 B
  float*  beta        = (float*)(ws + 121634816);              //    262,144 B

  rope_kernel<<<dim3(32768), dim3(256), 0, stream>>>(Q, QR);
  transpose_cast_kernel<<<dim3(8, 32, 32), dim3(256), 0, stream>>>(V, Vt, 2048, 512);
  transpose_cast_kernel<<<dim3(8, 4, 32), dim3(256), 0, stream>>>(M0, M0t, 256, 512);
  qkm_kernel<<<dim3(128, 2), dim3(512), 0, stream>>>(x_raw, wq, wk, Qm, Km);
  beta_kernel<<<dim3(8192), dim3(64), 0, stream>>>(x_raw, bw, beta);
  scan_kernel<<<dim3(2048), dim3(64), 0, stream>>>(Km, x_next, beta, M0, Mout);
  attn_kernel<<<dim3(16, 32, 2), dim3(512), 0, stream>>>(QR, Vt, y);
  combine_kernel<<<dim3(32, 32), dim3(512), 0, stream>>>(Qm, M0t, mg, y);
}